// Round 6
// baseline (205.863 us; speedup 1.0000x reference)
//
#include <hip/hip_runtime.h>

// B=8, S=2048, IN=1024, H=1024
//   q  = vec @ wq_w^T + wq_b            [B,S,H]
//   ret= relu(q_b^T q_b) per batch      [B,H,H]   (registers only)
//   out= ret @ lin_w + lin_b            [B,H]
//
// Pipeline:
//   prep_small: out init + wq fp32->bf16 (tiny, ~2us)
//   gemm_q_vf:  vec staged fp32 via global_load_lds, converted to bf16 on the
//               LDS->VGPR read (round-half-up + v_perm). No vec pre-pass.
//   syrk_dot:   symmetric (ty<=tx), FULL K per block — relu is nonlinear, the
//               K reduction must complete before relu (R5 lesson: K-split = WRONG).

#define BM 128
#define BN 128

typedef short     bf16x8 __attribute__((ext_vector_type(8)));
typedef unsigned short u16x8 __attribute__((ext_vector_type(8)));
typedef float     f32x4 __attribute__((ext_vector_type(4)));

__device__ inline unsigned short f2bf(float f) {
  unsigned int u = __float_as_uint(f);
  u += 0x7fffu + ((u >> 16) & 1u);   // RNE
  return (unsigned short)(u >> 16);
}

__device__ inline u16x8 pack8(float4 a, float4 b) {
  u16x8 r;
  r[0] = f2bf(a.x); r[1] = f2bf(a.y); r[2] = f2bf(a.z); r[3] = f2bf(a.w);
  r[4] = f2bf(b.x); r[5] = f2bf(b.y); r[6] = f2bf(b.z); r[7] = f2bf(b.w);
  return r;
}

__device__ inline void async16(void* lds, const void* g) {
  __builtin_amdgcn_global_load_lds(
      (const __attribute__((address_space(1))) void*)g,
      (__attribute__((address_space(3))) void*)lds,
      16, 0, 0);
}

// two fp32 (as uint bits) -> packed bf16 pair, round-half-up
__device__ inline unsigned int pk2(unsigned int lo, unsigned int hi) {
  return __builtin_amdgcn_perm(hi + 0x8000u, lo + 0x8000u, 0x07060302u);
}

// out init (8192) + wq fp32->bf16 (131072 groups of 8), one tiny launch
__global__ __launch_bounds__(256) void prep_small(
    const float* __restrict__ wq, unsigned short* __restrict__ wqbf,
    const float* __restrict__ lin_b, float* __restrict__ out)
{
  const int i = blockIdx.x * 256 + threadIdx.x;
  const float4* s = (const float4*)(wq + (size_t)i * 8);
  float4 a = s[0], b = s[1];
  *(u16x8*)(wqbf + (size_t)i * 8) = pack8(a, b);
  if (i < 8192) out[i] = lin_b[0];
}

__global__ void init_out(float* __restrict__ out, const float* __restrict__ lin_b) {
  int i = blockIdx.x * 256 + threadIdx.x;
  if (i < 8192) out[i] = lin_b[0];
}

// ------- gemm_q_vf: qT = wqbf * vec^T + bias, vec converted in-kernel -------
// A = wqbf [1024,1024] bf16 K-contig; B = vec [16384,1024] fp32 K-contig.
// Output qT bf16 [1024][16384].
__global__ __launch_bounds__(256) void gemm_q_vf(
    const unsigned short* __restrict__ A, const float* __restrict__ V,
    const float* __restrict__ bias, unsigned short* __restrict__ qT)
{
  __shared__ unsigned short As[BM * 32];  // 8 KB bf16
  __shared__ float          Bs[BN * 32];  // 16 KB fp32

  const int m0 = blockIdx.y * BM;
  const int n0 = blockIdx.x * BN;
  const int t    = threadIdx.x;
  const int lane = t & 63;
  const int wave = t >> 6;
  const int wm = (wave >> 1) * 64;
  const int wn = (wave & 1) * 64;
  const int quad = lane >> 4;
  const int lrow = lane & 15;

  // A staging (bf16, 2 issues): rows t>>2 (+64), 16B chunk (t&3)^((row>>1)&3)
  const int sa_row = t >> 2;
  const int sa_col = (((t & 3) ^ ((sa_row >> 1) & 3)) << 3);   // shorts
  const unsigned short* gA0 = A + (size_t)(m0 + sa_row) * 1024 + sa_col;
  const unsigned short* gA1 = gA0 + (size_t)64 * 1024;

  // B staging (fp32, 4 issues): rows t>>3 (+32p), 16B chunk (t&7)^(row&7)
  const int sb_row = t >> 3;                                   // 0..31
  const int sb_chunk = (t & 7) ^ (sb_row & 7);
  const float* gB = V + (size_t)(n0 + sb_row) * 1024 + sb_chunk * 4;

  // read-side indices
  const int rcA = (quad ^ ((lrow >> 1) & 3)) << 3;   // A chunk (shorts)
  const int m7  = lrow & 7;
  const int sB0 = ((2 * quad) ^ m7) * 4;             // B chunk 2q (floats)
  const int sB1 = ((2 * quad + 1) ^ m7) * 4;         // B chunk 2q+1 (floats)

  f32x4 acc[4][4];
#pragma unroll
  for (int i = 0; i < 4; ++i)
#pragma unroll
    for (int j = 0; j < 4; ++j) acc[i][j] = (f32x4){0.f, 0.f, 0.f, 0.f};

  for (int k0 = 0; k0 < 1024; k0 += 32) {
    async16(&As[t * 8],        gA0 + k0);
    async16(&As[2048 + t * 8], gA1 + k0);
#pragma unroll
    for (int p = 0; p < 4; ++p)
      async16(&Bs[p * 1024 + t * 4], gB + (size_t)p * 32 * 1024 + k0);
    __syncthreads();

    bf16x8 af[4], bfr[4];
#pragma unroll
    for (int i = 0; i < 4; ++i)
      af[i] = *(const bf16x8*)&As[(wm + i * 16 + lrow) * 32 + rcA];
#pragma unroll
    for (int j = 0; j < 4; ++j) {
      const float* br = &Bs[(wn + j * 16 + lrow) * 32];
      const uint4 u0 = *(const uint4*)(br + sB0);   // k elems 8q..8q+4
      const uint4 u1 = *(const uint4*)(br + sB1);   // k elems 8q+4..8q+8
      union { unsigned int u[4]; bf16x8 v; } tmp;
      tmp.u[0] = pk2(u0.x, u0.y);
      tmp.u[1] = pk2(u0.z, u0.w);
      tmp.u[2] = pk2(u1.x, u1.y);
      tmp.u[3] = pk2(u1.z, u1.w);
      bfr[j] = tmp.v;
    }
#pragma unroll
    for (int i = 0; i < 4; ++i)
#pragma unroll
      for (int j = 0; j < 4; ++j)
        acc[i][j] = __builtin_amdgcn_mfma_f32_16x16x32_bf16(af[i], bfr[j], acc[i][j], 0, 0, 0);
    __syncthreads();
  }

#pragma unroll
  for (int i = 0; i < 4; ++i) {
    const int mb = m0 + wm + i * 16 + quad * 4;
#pragma unroll
    for (int r = 0; r < 4; ++r) {
      const float bv = bias[mb + r];
#pragma unroll
      for (int j = 0; j < 4; ++j) {
        const int n = n0 + wn + j * 16 + lrow;
        qT[(size_t)(mb + r) * 16384 + n] = f2bf(acc[i][j][r] + bv);
      }
    }
  }
}

// ------- fallback gemm_q (fused fp32->bf16 inline), used if ws too small -------
__global__ __launch_bounds__(256) void gemm_q_fused(
    const float* __restrict__ Wq, const float* __restrict__ V,
    const float* __restrict__ bias, unsigned short* __restrict__ qT)
{
  __shared__ unsigned short As[BM * 32];
  __shared__ unsigned short Bs[BN * 32];

  const int m0 = blockIdx.y * BM;
  const int n0 = blockIdx.x * BN;
  const int t    = threadIdx.x;
  const int lane = t & 63;
  const int wave = t >> 6;
  const int wm = (wave >> 1) * 64;
  const int wn = (wave & 1) * 64;
  const int quad = lane >> 4;
  const int lrow = lane & 15;

  const int sr = t >> 1;
  const int sc = (t & 1) << 4;
  const float* gA = Wq + (size_t)(m0 + sr) * 1024 + sc;
  const float* gB = V  + (size_t)(n0 + sr) * 1024 + sc;

  f32x4 acc[4][4];
#pragma unroll
  for (int i = 0; i < 4; ++i)
#pragma unroll
    for (int j = 0; j < 4; ++j) acc[i][j] = (f32x4){0.f, 0.f, 0.f, 0.f};

  for (int k0 = 0; k0 < 1024; k0 += 32) {
    const float4* a4 = (const float4*)(gA + k0);
    const float4* b4 = (const float4*)(gB + k0);
    float4 av0 = a4[0], av1 = a4[1], av2 = a4[2], av3 = a4[3];
    float4 bv0 = b4[0], bv1 = b4[1], bv2 = b4[2], bv3 = b4[3];
    *(u16x8*)&As[sr * 32 + sc]     = pack8(av0, av1);
    *(u16x8*)&As[sr * 32 + sc + 8] = pack8(av2, av3);
    *(u16x8*)&Bs[sr * 32 + sc]     = pack8(bv0, bv1);
    *(u16x8*)&Bs[sr * 32 + sc + 8] = pack8(bv2, bv3);
    __syncthreads();

    bf16x8 af[4], bfr[4];
#pragma unroll
    for (int i = 0; i < 4; ++i)
      af[i] = *(const bf16x8*)&As[(wm + i * 16 + lrow) * 32 + quad * 8];
#pragma unroll
    for (int j = 0; j < 4; ++j)
      bfr[j] = *(const bf16x8*)&Bs[(wn + j * 16 + lrow) * 32 + quad * 8];
#pragma unroll
    for (int i = 0; i < 4; ++i)
#pragma unroll
      for (int j = 0; j < 4; ++j)
        acc[i][j] = __builtin_amdgcn_mfma_f32_16x16x32_bf16(af[i], bfr[j], acc[i][j], 0, 0, 0);
    __syncthreads();
  }

#pragma unroll
  for (int i = 0; i < 4; ++i) {
    const int mb = m0 + wm + i * 16 + quad * 4;
#pragma unroll
    for (int r = 0; r < 4; ++r) {
      const float bv = bias[mb + r];
#pragma unroll
      for (int j = 0; j < 4; ++j) {
        const int n = n0 + wn + j * 16 + lrow;
        qT[(size_t)(mb + r) * 16384 + n] = f2bf(acc[i][j][r] + bv);
      }
    }
  }
}

// ---------------- syrk_dot: symmetric, FULL K, LDS BK=64 ----------------
// job blockIdx.x in [0,36): tile pair (tx,ty) with ty<=tx. Diagonal: row-pass only.
__global__ __launch_bounds__(256) void syrk_dot(
    const unsigned short* __restrict__ qT, const float* __restrict__ W,
    float* __restrict__ out)
{
  __shared__ unsigned short As[BM * 64];
  __shared__ unsigned short Bs[BN * 64];

  const int bb = blockIdx.z;
  const int job = blockIdx.x;
  int tx = 0;
  while ((tx + 1) * (tx + 2) / 2 <= job) ++tx;
  const int ty = job - tx * (tx + 1) / 2;
  const int x0 = tx * BM;
  const int y0 = ty * BN;
  const bool diag = (tx == ty);

  const int t    = threadIdx.x;
  const int lane = t & 63;
  const int wave = t >> 6;
  const int wm = (wave >> 1) * 64;
  const int wn = (wave & 1) * 64;
  const int quad = lane >> 4;
  const int lrow = lane & 15;

  const int srow = t >> 3;                              // 0..31
  const int gcol = (((t & 7) ^ (srow & 7)) << 3);       // shorts
  const size_t cbase = (size_t)bb * 2048 + gcol;
  const unsigned short* gA = qT + (size_t)(x0 + srow) * 16384 + cbase;
  const unsigned short* gB = qT + (size_t)(y0 + srow) * 16384 + cbase;

  f32x4 acc[4][4];
#pragma unroll
  for (int i = 0; i < 4; ++i)
#pragma unroll
    for (int j = 0; j < 4; ++j) acc[i][j] = (f32x4){0.f, 0.f, 0.f, 0.f};

  for (int k0 = 0; k0 < 2048; k0 += 64) {
#pragma unroll
    for (int p = 0; p < 4; ++p) {
      async16(&As[p * 2048 + t * 8], gA + (size_t)p * 32 * 16384 + k0);
      async16(&Bs[p * 2048 + t * 8], gB + (size_t)p * 32 * 16384 + k0);
    }
    __syncthreads();

#pragma unroll
    for (int kk = 0; kk < 2; ++kk) {
      const int rc = (((kk * 4 + quad) ^ (lrow & 7)) << 3);  // shorts
      bf16x8 af[4], bfr[4];
#pragma unroll
      for (int i = 0; i < 4; ++i)
        af[i] = *(const bf16x8*)&As[(wm + i * 16 + lrow) * 64 + rc];
#pragma unroll
      for (int j = 0; j < 4; ++j)
        bfr[j] = *(const bf16x8*)&Bs[(wn + j * 16 + lrow) * 64 + rc];
#pragma unroll
      for (int i = 0; i < 4; ++i)
#pragma unroll
        for (int j = 0; j < 4; ++j)
          acc[i][j] = __builtin_amdgcn_mfma_f32_16x16x32_bf16(af[i], bfr[j], acc[i][j], 0, 0, 0);
    }
    __syncthreads();
  }

  float* ob = out + bb * 1024;

  // row pass: out[x] += sum_y relu(C[x,y]) * W[y]
  float wv[4];
#pragma unroll
  for (int j = 0; j < 4; ++j) wv[j] = W[y0 + wn + j * 16 + lrow];

#pragma unroll
  for (int i = 0; i < 4; ++i) {
#pragma unroll
    for (int r = 0; r < 4; ++r) {
      float p = 0.f;
#pragma unroll
      for (int j = 0; j < 4; ++j) {
        float v = acc[i][j][r];
        v = v > 0.f ? v : 0.f;
        p += v * wv[j];
      }
#pragma unroll
      for (int off = 1; off < 16; off <<= 1) p += __shfl_xor(p, off, 64);
      if (lrow == 0)
        atomicAdd(&ob[x0 + wm + i * 16 + quad * 4 + r], p);
    }
  }

  // col pass (off-diagonal only): out[y] += sum_x relu(C[x,y]) * W[x]
  if (!diag) {
    float wx[4][4];
#pragma unroll
    for (int i = 0; i < 4; ++i)
#pragma unroll
      for (int r = 0; r < 4; ++r)
        wx[i][r] = W[x0 + wm + i * 16 + quad * 4 + r];

#pragma unroll
    for (int j = 0; j < 4; ++j) {
      float pc = 0.f;
#pragma unroll
      for (int i = 0; i < 4; ++i)
#pragma unroll
        for (int r = 0; r < 4; ++r) {
          float v = acc[i][j][r];
          v = v > 0.f ? v : 0.f;
          pc += v * wx[i][r];
        }
      pc += __shfl_xor(pc, 16, 64);
      pc += __shfl_xor(pc, 32, 64);
      if (quad == 0)
        atomicAdd(&ob[y0 + wn + j * 16 + lrow], pc);
    }
  }
}

extern "C" void kernel_launch(void* const* d_in, const int* in_sizes, int n_in,
                              void* d_out, int out_size, void* d_ws, size_t ws_size,
                              hipStream_t stream) {
  const float* vec   = (const float*)d_in[0];  // [8,2048,1024]
  const float* wq_w  = (const float*)d_in[1];  // [1024,1024]
  const float* wq_b  = (const float*)d_in[2];  // [1024]
  const float* lin_w = (const float*)d_in[3];  // [1,1024]
  const float* lin_b = (const float*)d_in[4];  // [1]
  float* out = (float*)d_out;                  // [8,1024]

  unsigned short* qT = (unsigned short*)d_ws;                    // 32 MiB
  const size_t need = (size_t)(32 + 2) * 1024 * 1024;

  if (ws_size >= need) {
    unsigned short* wqbf = qT + (size_t)16 * 1024 * 1024;        // 2 MiB
    prep_small<<<dim3(512), dim3(256), 0, stream>>>(wq_w, wqbf, lin_b, out);
    gemm_q_vf<<<dim3(128, 8), dim3(256), 0, stream>>>(wqbf, vec, wq_b, qT);
  } else {
    init_out<<<dim3(32), dim3(256), 0, stream>>>(out, lin_b);
    gemm_q_fused<<<dim3(128, 8), dim3(256), 0, stream>>>(wq_w, vec, wq_b, qT);
  }
  syrk_dot<<<dim3(36, 1, 8), dim3(256), 0, stream>>>(qT, lin_w, out);
}